// Round 7
// baseline (1853.150 us; speedup 1.0000x reference)
//
#include <hip/hip_runtime.h>
#include <math.h>

// Gated DeltaNet (chunked delta rule, CHUNK=64) for B=2,S=4096,H=16,Dk=Dv=128 fp32.
// Round 7 = round 5 resubmitted (infra failures rounds 5-6; pipeline never measured):
// scan software-pipelined — chunk n+1 operands prefetched to registers during
// chunk n compute, drained to LDS post-B1/post-B2 where buffers are dead.
// Prep unchanged from round 4.

#define CC 64

constexpr int B_  = 2;
constexpr int S_  = 4096;
constexpr int H_  = 16;
constexpr int DK_ = 128;
constexpr int DV_ = 128;
constexpr int NC_  = S_ / CC;        // 64 chunks per (b,h)
constexpr int NCH_ = B_ * H_ * NC_;  // 2048 chunks total
constexpr int W_   = 16;             // dv-block width in kernel 2
constexpr int NWB_ = DV_ / W_;       // 8 dv blocks

constexpr float QSCALE = 0.08838834764831845f;  // 1/sqrt(128)

// workspace layout (float offsets) — total 168,296,448 bytes
constexpr size_t WS_KCUM = 0;                                   // [NCH][64][128]
constexpr size_t WS_VUT  = WS_KCUM + (size_t)NCH_ * CC * DK_;   // [NCH][64][128]
constexpr size_t WS_ATT  = WS_VUT  + (size_t)NCH_ * CC * DV_;   // [NCH][64][64]
constexpr size_t WS_GC   = WS_ATT  + (size_t)NCH_ * CC * CC;    // [NCH][64]

__device__ __forceinline__ void ld4(float* d, const float* s) {
    float4 t = *(const float4*)s;
    d[0] = t.x; d[1] = t.y; d[2] = t.z; d[3] = t.w;
}
__device__ __forceinline__ void st4(float* d, const float* s) {
    *(float4*)d = make_float4(s[0], s[1], s[2], s[3]);
}

// ---------------------------------------------------------------------------
// Kernel 1: per-chunk preprocessing (unchanged from round 4)
// ---------------------------------------------------------------------------
__global__ __launch_bounds__(512) void gdn_prep(
    const float* __restrict__ q, const float* __restrict__ k,
    const float* __restrict__ v, const float* __restrict__ g,
    const float* __restrict__ beta, float* __restrict__ ws)
{
    const int cid = blockIdx.x;          // (b*H + h)*NC + n
    const int n   = cid & (NC_ - 1);
    const int bh  = cid / NC_;
    const int h   = bh & (H_ - 1);
    const int b   = bh / H_;
    const int t   = threadIdx.x;
    const int s0  = n * CC;

    __shared__ float s_k[CC][132];   // kn; later in-place u2 (k_cumdecay)
    __shared__ float s_q[CC][132];   // qn*QSCALE; later u1 (v_ut)
    __shared__ float s_A[CC][66];    // A strict lower
    __shared__ float s_at[CC][68];   // attn staging (coalesced global store)
    __shared__ float s_gc[CC];
    __shared__ float s_beta[CC];

    if (t < CC) {
        const size_t gi = ((size_t)b * S_ + s0 + t) * H_ + h;
        float gv = g[gi];
        float x = fminf(fmaxf(gv, -20.f), 20.f);
        s_beta[t] = beta[gi];
#pragma unroll
        for (int o = 1; o < CC; o <<= 1) {
            float y = __shfl_up(x, o);
            if (t >= o) x += y;
        }
        s_gc[t] = x;
    }

    {
        const int i  = t >> 3;
        const int d0 = (t & 7) * 16;
        const size_t rb = (((size_t)b * S_ + s0 + i) * H_ + h) * (size_t)DK_;
        float qr[4][4], kr[4][4];
        float ssq = 0.f, ssk = 0.f;
#pragma unroll
        for (int j4 = 0; j4 < 4; ++j4) {
            ld4(qr[j4], q + rb + d0 + j4 * 4);
            ld4(kr[j4], k + rb + d0 + j4 * 4);
#pragma unroll
            for (int c = 0; c < 4; ++c) { ssq += qr[j4][c] * qr[j4][c]; ssk += kr[j4][c] * kr[j4][c]; }
        }
        ssq += __shfl_xor(ssq, 1); ssq += __shfl_xor(ssq, 2); ssq += __shfl_xor(ssq, 4);
        ssk += __shfl_xor(ssk, 1); ssk += __shfl_xor(ssk, 2); ssk += __shfl_xor(ssk, 4);
        const float rq = QSCALE / sqrtf(ssq + 1e-6f);
        const float rk = 1.0f   / sqrtf(ssk + 1e-6f);
#pragma unroll
        for (int j4 = 0; j4 < 4; ++j4) {
            float tq[4], tk[4];
#pragma unroll
            for (int c = 0; c < 4; ++c) { tq[c] = qr[j4][c] * rq; tk[c] = kr[j4][c] * rk; }
            st4(&s_q[i][d0 + j4 * 4], tq);
            st4(&s_k[i][d0 + j4 * 4], tk);
        }
    }
    __syncthreads();

    {
        const int ks   = t & 1;
        const int slot = t >> 1;
        const int tj = (slot & 7) | (((slot >> 5) & 1) << 3);
        const int ti = ((slot >> 3) & 3) | ((slot >> 6) << 2);
        const int i0 = ti * 4, j0 = tj * 4;
        float dq[4][4] = {}, dkk[4][4] = {};
        if (j0 <= i0 + 3) {
            for (int s = 0; s < 16; ++s) {
                const int dd = (ks + 2 * s) * 4;
                float qa[4][4], ka[4][4], kb[4][4];
#pragma unroll
                for (int r = 0; r < 4; ++r) { ld4(qa[r], &s_q[i0 + r][dd]); ld4(ka[r], &s_k[i0 + r][dd]); }
#pragma unroll
                for (int c = 0; c < 4; ++c) ld4(kb[c], &s_k[j0 + c][dd]);
#pragma unroll
                for (int r = 0; r < 4; ++r)
#pragma unroll
                    for (int c = 0; c < 4; ++c) {
                        dq[r][c]  += qa[r][0]*kb[c][0] + qa[r][1]*kb[c][1] + qa[r][2]*kb[c][2] + qa[r][3]*kb[c][3];
                        dkk[r][c] += ka[r][0]*kb[c][0] + ka[r][1]*kb[c][1] + ka[r][2]*kb[c][2] + ka[r][3]*kb[c][3];
                    }
            }
        }
#pragma unroll
        for (int r = 0; r < 4; ++r)
#pragma unroll
            for (int c = 0; c < 4; ++c) {
                float x = dq[r][c];  x += __shfl_xor(x, 1); dq[r][c] = x;
                float y = dkk[r][c]; y += __shfl_xor(y, 1); dkk[r][c] = y;
            }
#pragma unroll
        for (int r = 0; r < 4; ++r)
#pragma unroll
            for (int cc = 0; cc < 2; ++cc) {
                const int c = ks * 2 + cc;
                const int i = i0 + r, j = j0 + c;
                float av = 0.f;
                if (j <= i) {
                    const float dec = expf(s_gc[i] - s_gc[j]);
                    av = dq[r][c] * dec;
                    if (j < i) s_A[i][j] = -(s_beta[i] * dkk[r][c]) * dec;
                }
                s_at[i][j] = av;
            }
    }
    __syncthreads();

    {
        const size_t vb = (((size_t)b * S_ + s0) * H_ + h) * (size_t)DV_;
#pragma unroll
        for (int r = 0; r < 4; ++r) {
            const int f4i = r * 512 + t;           // 2048 float4s
            const int row = f4i >> 5, c4 = (f4i & 31) * 4;
            float tv[4];
            ld4(tv, v + vb + (size_t)row * H_ * DV_ + c4);
            const float be = s_beta[row];
            tv[0] *= be; tv[1] *= be; tv[2] *= be; tv[3] *= be;
            st4(&s_q[row][c4], tv);
            float tk[4];
            ld4(tk, &s_k[row][c4]);
            const float sc = be * expf(s_gc[row]);
            tk[0] *= sc; tk[1] *= sc; tk[2] *= sc; tk[3] *= sc;
            st4(&s_k[row][c4], tk);
        }
    }
    __syncthreads();

    if (t < 256) {
        const int d = t & 127;
        float* u = (t < 128) ? &s_q[0][0] : &s_k[0][0];
        for (int blk = 0; blk < 16; ++blk) {
            const int i0 = blk * 4;
            const float u0 = u[(i0 + 0) * 132 + d];
            const float u1 = u[(i0 + 1) * 132 + d] + s_A[i0 + 1][i0] * u0;
            const float u2 = u[(i0 + 2) * 132 + d] + s_A[i0 + 2][i0] * u0 + s_A[i0 + 2][i0 + 1] * u1;
            const float u3 = u[(i0 + 3) * 132 + d] + s_A[i0 + 3][i0] * u0 + s_A[i0 + 3][i0 + 1] * u1
                                                   + s_A[i0 + 3][i0 + 2] * u2;
            u[(i0 + 1) * 132 + d] = u1;
            u[(i0 + 2) * 132 + d] = u2;
            u[(i0 + 3) * 132 + d] = u3;
            for (int i = i0 + 4; i < CC; ++i) {
                const float* Ai = s_A[i];
                u[i * 132 + d] += Ai[i0] * u0 + Ai[i0 + 1] * u1 + Ai[i0 + 2] * u2 + Ai[i0 + 3] * u3;
            }
        }
    }
    __syncthreads();

    {
        const size_t kcb = WS_KCUM + (size_t)cid * CC * DK_;
        const size_t vub = WS_VUT  + (size_t)cid * CC * DV_;
#pragma unroll
        for (int r = 0; r < 4; ++r) {
            const int f4i = r * 512 + t;
            const int row = f4i >> 5, c4 = (f4i & 31) * 4;
            float tk[4], tv[4];
            ld4(tk, &s_k[row][c4]);
            ld4(tv, &s_q[row][c4]);
            st4((float*)(ws + kcb) + f4i * 4, tk);
            st4((float*)(ws + vub) + f4i * 4, tv);
        }
        const size_t atb = WS_ATT + (size_t)cid * CC * CC;
#pragma unroll
        for (int r = 0; r < 2; ++r) {
            const int f4i = r * 512 + t;           // 1024 float4s
            const int row = f4i >> 4, c4 = (f4i & 15) * 4;
            float ta[4];
            ld4(ta, &s_at[row][c4]);
            st4((float*)(ws + atb) + f4i * 4, ta);
        }
        if (t < CC) ws[WS_GC + (size_t)cid * CC + t] = s_gc[t];
    }
}

// ---------------------------------------------------------------------------
// Kernel 2: sequential inter-chunk scan, software-pipelined.
// One WG per (b,h,dv-block of 16), 512 threads (8 waves), 2 barriers/chunk.
// Chunk n+1 operands are prefetched to regs during chunk n compute and drained
// to LDS where the buffer is dead: s_kq after B1 (consumed only in phase C),
// s_kd/s_at after B2 (consumed only in phase D).
// ---------------------------------------------------------------------------
__global__ __launch_bounds__(512, 2) void gdn_scan(
    const float* __restrict__ q, const float* __restrict__ k,
    const float* __restrict__ ws, float* __restrict__ out)
{
    const int bh  = blockIdx.x & 31;
    const int wb  = blockIdx.x >> 5;
    const int h   = bh & (H_ - 1);
    const int b   = bh / H_;
    const int dv0 = wb * W_;
    const int t   = threadIdx.x;

    const int ks   = t & 3;            // k-split lane (quad)
    const int slot = t >> 2;           // 128 slots
    const int jg   = slot & 3;         // dp group
    const int mg   = slot >> 2;        // 0..31
    const int dp0  = jg * 4;

    const int irow = t >> 3;           // 0..63, q/k staging row
    const int d0   = (t & 7) * 16;     // q/k staging col base

    __shared__ float s_kq[128][132];   // rows 0-63: kc, rows 64-127: qg
    __shared__ float s_kd[64][132];    // kn * e^(gl-gc), row-major
    __shared__ float s_at[64][68];     // attn
    __shared__ float s_st[128][20];    // state [dk][dp]
    __shared__ float s_vn[64][20];     // v_new [i][dp]
    __shared__ float s_o[64][20];      // inter (qg . state) [i][dp]

    // prefetch registers (chunk n+1 operands, in flight during chunk n compute)
    float pf_kc[4][4];                 // kc staging share (4 float4)
    float pf_q[4][4], pf_k[4][4];      // raw q/k row slice
    float pf_at[2][4];                 // attn staging share
    float vut_[4][4];                  // vut tile (ks==0 && mg<16 lanes only)
    float gci_n, gl_n;                 // gc[irow], gc[63] of prefetched chunk
    float rkd_sv;                      // kd row scale, computed post-B1
    float egl_cur;                     // e^{gl} of current chunk

    auto issue_main = [&](int cc) {    // kc, att, q, k, gc — not vut
        const int cid = bh * NC_ + cc;
        const float* kcb = ws + WS_KCUM + (size_t)cid * CC * DK_;
#pragma unroll
        for (int r = 0; r < 4; ++r) ld4(pf_kc[r], kcb + (r * 512 + t) * 4);
        const float* atb = ws + WS_ATT + (size_t)cid * CC * CC;
#pragma unroll
        for (int r = 0; r < 2; ++r) ld4(pf_at[r], atb + (r * 512 + t) * 4);
        const size_t rb = (((size_t)b * S_ + (size_t)cc * CC + irow) * H_ + h) * (size_t)DK_;
#pragma unroll
        for (int j4 = 0; j4 < 4; ++j4) {
            ld4(pf_q[j4], q + rb + d0 + j4 * 4);
            ld4(pf_k[j4], k + rb + d0 + j4 * 4);
        }
        gci_n = ws[WS_GC + (size_t)cid * CC + irow];
        gl_n  = ws[WS_GC + (size_t)cid * CC + (CC - 1)];
    };
    auto issue_vut = [&](int cc) {     // after phase C consumed vut_
        if (ks == 0 && mg < 16) {
            const float* vub = ws + WS_VUT + (size_t)(bh * NC_ + cc) * CC * DV_;
            const int i0 = mg * 4;
#pragma unroll
            for (int r = 0; r < 4; ++r) ld4(vut_[r], vub + (size_t)(i0 + r) * DV_ + dv0 + dp0);
        }
    };
    auto stage_kq = [&]() {            // post-B1: s_kq is dead; write kc + qg
#pragma unroll
        for (int r = 0; r < 4; ++r) {
            const int f4i = r * 512 + t;
            st4(&s_kq[f4i >> 5][(f4i & 31) * 4], pf_kc[r]);
        }
        float ssq = 0.f, ssk = 0.f;
#pragma unroll
        for (int j4 = 0; j4 < 4; ++j4)
#pragma unroll
            for (int c = 0; c < 4; ++c) {
                ssq += pf_q[j4][c] * pf_q[j4][c];
                ssk += pf_k[j4][c] * pf_k[j4][c];
            }
        ssq += __shfl_xor(ssq, 1); ssq += __shfl_xor(ssq, 2); ssq += __shfl_xor(ssq, 4);
        ssk += __shfl_xor(ssk, 1); ssk += __shfl_xor(ssk, 2); ssk += __shfl_xor(ssk, 4);
        const float rq = QSCALE / sqrtf(ssq + 1e-6f) * expf(gci_n);
        rkd_sv = expf(gl_n - gci_n) / sqrtf(ssk + 1e-6f);
#pragma unroll
        for (int j4 = 0; j4 < 4; ++j4) {
            float tq[4];
#pragma unroll
            for (int c = 0; c < 4; ++c) tq[c] = pf_q[j4][c] * rq;
            st4(&s_kq[64 + irow][d0 + j4 * 4], tq);
        }
    };
    auto stage_kdat = [&]() {          // post-B2: s_kd/s_at dead; write kd + att
#pragma unroll
        for (int j4 = 0; j4 < 4; ++j4) {
            float tk[4];
#pragma unroll
            for (int c = 0; c < 4; ++c) tk[c] = pf_k[j4][c] * rkd_sv;
            st4(&s_kd[irow][d0 + j4 * 4], tk);
        }
#pragma unroll
        for (int r = 0; r < 2; ++r) {
            const int f4i = r * 512 + t;
            st4(&s_at[f4i >> 4][(f4i & 15) * 4], pf_at[r]);
        }
    };

    // ---------------- prologue: chunk 0 ----------------
    for (int p = t; p < 128 * 20; p += 512) (&s_st[0][0])[p] = 0.f;
    issue_main(0);
    issue_vut(0);
    stage_kq();
    stage_kdat();
    egl_cur = expf(gl_n);
    __syncthreads();

    for (int n = 0; n < NC_; ++n) {
        const int s0   = n * CC;
        const bool more = (n + 1 < NC_);
        if (more) issue_main(n + 1);   // loads in flight across C, B1

        // ---------------- Phase C: X = [kc;qg](128x128) . st(128x16) --------
        {
            const int m0 = mg * 4;
            float acc[4][4] = {};
            for (int s = 0; s < 8; ++s) {
                const int dk = (ks + 4 * s) * 4;
                float Bv[4][4], Av[4][4];
#pragma unroll
                for (int kk = 0; kk < 4; ++kk) ld4(Bv[kk], &s_st[dk + kk][dp0]);
#pragma unroll
                for (int r = 0; r < 4; ++r) ld4(Av[r], &s_kq[m0 + r][dk]);
#pragma unroll
                for (int r = 0; r < 4; ++r)
#pragma unroll
                    for (int c = 0; c < 4; ++c)
                        acc[r][c] += Av[r][0]*Bv[0][c] + Av[r][1]*Bv[1][c]
                                   + Av[r][2]*Bv[2][c] + Av[r][3]*Bv[3][c];
            }
#pragma unroll
            for (int r = 0; r < 4; ++r)
#pragma unroll
                for (int c = 0; c < 4; ++c) {
                    float x = acc[r][c];
                    x += __shfl_xor(x, 1); x += __shfl_xor(x, 2);
                    acc[r][c] = x;
                }
            if (ks == 0) {
                if (mg < 16) {           // v_new rows
                    const int i0 = mg * 4;
#pragma unroll
                    for (int r = 0; r < 4; ++r) {
                        float tv[4];
#pragma unroll
                        for (int c = 0; c < 4; ++c) tv[c] = vut_[r][c] - acc[r][c];
                        st4(&s_vn[i0 + r][dp0], tv);
                    }
                } else {                 // inter rows
                    const int i0 = (mg - 16) * 4;
#pragma unroll
                    for (int r = 0; r < 4; ++r) st4(&s_o[i0 + r][dp0], acc[r]);
                }
            }
        }
        if (more) issue_vut(n + 1);    // vut_ consumed above; reload for n+1
        __syncthreads();   // B1
        if (more) stage_kq();          // s_kq dead after B1; also l2norm compute

        // ---------------- Phase D: out + state update ----------------------
        {
            const int i0b = mg * 2;
            float bacc[2][4] = {};
            for (int s = 0; s < 4; ++s) {
                const int j = (ks + 4 * s) * 4;
                float vnv[4][4], atv[2][4];
#pragma unroll
                for (int kk = 0; kk < 4; ++kk) ld4(vnv[kk], &s_vn[j + kk][dp0]);
#pragma unroll
                for (int r = 0; r < 2; ++r) ld4(atv[r], &s_at[i0b + r][j]);
#pragma unroll
                for (int r = 0; r < 2; ++r)
#pragma unroll
                    for (int c = 0; c < 4; ++c)
                        bacc[r][c] += atv[r][0]*vnv[0][c] + atv[r][1]*vnv[1][c]
                                    + atv[r][2]*vnv[2][c] + atv[r][3]*vnv[3][c];
            }
#pragma unroll
            for (int r = 0; r < 2; ++r)
#pragma unroll
                for (int c = 0; c < 4; ++c) {
                    float x = bacc[r][c];
                    x += __shfl_xor(x, 1); x += __shfl_xor(x, 2);
                    bacc[r][c] = x;
                }
            if (ks == 0) {
#pragma unroll
                for (int r = 0; r < 2; ++r) {
                    float ov[4];
                    ld4(ov, &s_o[i0b + r][dp0]);
#pragma unroll
                    for (int c = 0; c < 4; ++c) ov[c] += bacc[r][c];
                    st4(out + (((size_t)b * S_ + s0 + i0b + r) * H_ + h) * (size_t)DV_ + dv0 + dp0, ov);
                }
            }
        }
        {
            const int dk0 = mg * 4;
            float cacc[4][4] = {};
            for (int s = 0; s < 4; ++s) {
                const int ib = (ks + 4 * s) * 4;
#pragma unroll
                for (int kk = 0; kk < 4; ++kk) {
                    float kdv[4], vnv[4];
                    ld4(kdv, &s_kd[ib + kk][dk0]);
                    ld4(vnv, &s_vn[ib + kk][dp0]);
#pragma unroll
                    for (int r = 0; r < 4; ++r)
#pragma unroll
                        for (int c = 0; c < 4; ++c)
                            cacc[r][c] += kdv[r] * vnv[c];
                }
            }
#pragma unroll
            for (int r = 0; r < 4; ++r)
#pragma unroll
                for (int c = 0; c < 4; ++c) {
                    float x = cacc[r][c];
                    x += __shfl_xor(x, 1); x += __shfl_xor(x, 2);
                    cacc[r][c] = x;
                }
            if (ks == 0) {
#pragma unroll
                for (int r = 0; r < 4; ++r) {
                    float st_[4];
                    ld4(st_, &s_st[dk0 + r][dp0]);
#pragma unroll
                    for (int c = 0; c < 4; ++c) st_[c] = st_[c] * egl_cur + cacc[r][c];
                    st4(&s_st[dk0 + r][dp0], st_);
                }
            }
        }
        __syncthreads();   // B2
        if (more) {                      // s_kd/s_at dead after B2
            stage_kdat();
            egl_cur = expf(gl_n);
        }
    }
}

// ---------------------------------------------------------------------------
extern "C" void kernel_launch(void* const* d_in, const int* in_sizes, int n_in,
                              void* d_out, int out_size, void* d_ws, size_t ws_size,
                              hipStream_t stream) {
    const float* q    = (const float*)d_in[0];
    const float* k    = (const float*)d_in[1];
    const float* v    = (const float*)d_in[2];
    const float* g    = (const float*)d_in[3];
    const float* beta = (const float*)d_in[4];
    float* ws  = (float*)d_ws;
    float* out = (float*)d_out;

    gdn_prep<<<NCH_, 512, 0, stream>>>(q, k, v, g, beta, ws);
    gdn_scan<<<B_ * H_ * NWB_, 512, 0, stream>>>(q, k, ws, out);
}